// Round 1
// 364.621 us; speedup vs baseline: 1.2186x; 1.2186x over previous
//
#include <hip/hip_runtime.h>

constexpr int kB = 4;
constexpr int kF = 1025;
constexpr int kC = 6;
constexpr int kT = 1000;
constexpr int NPAIR = 15;
// Per-group accumulator layout: [0..5] diag, [6..20] re, [21..35] im, [36] masksum
constexpr int NACCG = 37;
constexpr int THREADS = 256;

__global__ __launch_bounds__(THREADS)
void mvdr_kernel(const float* __restrict__ spec_real,
                 const float* __restrict__ spec_imag,
                 const float* __restrict__ mask_s,
                 const float* __restrict__ mask_n,
                 float* __restrict__ out,
                 int spec_elems, int mask_elems, int out_elems) {
  const int bf   = blockIdx.x;
  const int tid  = threadIdx.x;
  const int lane = tid & 63;
  const int wave = tid >> 6;
  const int grp  = tid >> 7;      // 0 -> mask_s stats, 1 -> mask_n stats
  const int gtid = tid & 127;     // index within group

  __shared__ __align__(16) float sXr[kC * kT];   // 24 KB
  __shared__ __align__(16) float sXi[kC * kT];   // 24 KB
  __shared__ float sRed[4 * NACCG];
  // sFin layout (matches solver): [0..5] Sdiag, [6..20] Sre, [21..35] Sim,
  //                               [36..41] Ndiag, [42..56] Nre, [57..71] Nim,
  //                               [72] sumS, [73] sumN
  __shared__ float sFin[74];
  __shared__ float sW[2 * kC];

  const size_t sbase = (size_t)bf * (kC * kT);
  const size_t mbase = (size_t)bf * kT;

  const bool spec_ok = (sbase + (size_t)(kC * kT)) <= (size_t)spec_elems;
  const bool mask_ok = (mbase + (size_t)kT) <= (size_t)mask_elems;

  // ---- stage X slab into LDS ----
  if (spec_ok) {
    const float4* gr4 = reinterpret_cast<const float4*>(spec_real + sbase);
    const float4* gi4 = reinterpret_cast<const float4*>(spec_imag + sbase);
    float4* lr4 = reinterpret_cast<float4*>(sXr);
    float4* li4 = reinterpret_cast<float4*>(sXi);
    for (int i = tid; i < (kC * kT) / 4; i += THREADS) {
      lr4[i] = gr4[i];
      li4[i] = gi4[i];
    }
  } else {
    for (int i = tid; i < kC * kT; i += THREADS) { sXr[i] = 0.f; sXi[i] = 0.f; }
  }
  __syncthreads();

  // ---- PSD accumulation, split by half-block: grp 0 -> S, grp 1 -> N ----
  // 37 accumulators/thread (was 74) -> fits in VGPRs, no scratch spill.
  const float* __restrict__ mptr = (grp == 0) ? mask_s : mask_n;

  float acc[NACCG];
#pragma unroll
  for (int j = 0; j < NACCG; ++j) acc[j] = 0.f;

  for (int t = gtid; t < kT; t += 128) {
    float xr[kC], xi[kC];
#pragma unroll
    for (int c = 0; c < kC; ++c) {
      xr[c] = sXr[c * kT + t];
      xi[c] = sXi[c * kT + t];
    }
    float m = mask_ok ? mptr[mbase + t] : 0.f;
    acc[36] += m;
#pragma unroll
    for (int c = 0; c < kC; ++c) {
      float p = xr[c] * xr[c] + xi[c] * xi[c];
      acc[c] += m * p;
    }
    int k = 0;
#pragma unroll
    for (int c = 0; c < kC; ++c) {
#pragma unroll
      for (int e = c + 1; e < kC; ++e) {
        // psd[c][e] = X[c] * conj(X[e])
        float pr = xr[c] * xr[e] + xi[c] * xi[e];
        float pi = xi[c] * xr[e] - xr[c] * xi[e];
        acc[6  + k] += m * pr;
        acc[21 + k] += m * pi;
        ++k;
      }
    }
  }

  // ---- wave shuffle reduction, then cross-wave combine via LDS ----
#pragma unroll
  for (int j = 0; j < NACCG; ++j) {
    float v = acc[j];
#pragma unroll
    for (int off = 32; off > 0; off >>= 1)
      v += __shfl_down(v, off, 64);
    if (lane == 0) sRed[wave * NACCG + j] = v;
  }
  __syncthreads();
  if (tid < NACCG) {
    float s = sRed[tid]             + sRed[NACCG + tid];      // waves 0,1
    float n = sRed[2 * NACCG + tid] + sRed[3 * NACCG + tid];  // waves 2,3
    if (tid < 36) {
      sFin[tid]      = s;
      sFin[36 + tid] = n;
    } else {  // tid == 36: mask sums
      sFin[72] = s;
      sFin[73] = n;
    }
  }
  __syncthreads();

  // ---- thread 0: normalize, Tikhonov-load, Cholesky solve, weights ----
  if (tid == 0) {
    float isS = 1.f / (sFin[72] + 1e-15f);
    float isN = 1.f / (sFin[73] + 1e-15f);

    float trN = 0.f;
#pragma unroll
    for (int c = 0; c < kC; ++c) trN += sFin[36 + c];
    trN *= isN;
    float epsl = trN * 1e-7f + 1e-8f;

    float Sr[kC][kC], Si[kC][kC];
    float Ar[kC][kC], Ai[kC][kC];
#pragma unroll
    for (int c = 0; c < kC; ++c) {
      Sr[c][c] = sFin[c] * isS;             Si[c][c] = 0.f;
      Ar[c][c] = sFin[36 + c] * isN + epsl; Ai[c][c] = 0.f;
    }
    {
      int k = 0;
#pragma unroll
      for (int c = 0; c < kC; ++c) {
#pragma unroll
        for (int e = c + 1; e < kC; ++e) {
          float spr = sFin[6  + k] * isS, spi = sFin[21 + k] * isS;
          Sr[c][e] = spr;  Si[c][e] = spi;
          Sr[e][c] = spr;  Si[e][c] = -spi;
          float npr = sFin[42 + k] * isN, npi = sFin[57 + k] * isN;
          Ar[c][e] = npr;  Ai[c][e] = npi;
          Ar[e][c] = npr;  Ai[e][c] = -npi;
          ++k;
        }
      }
    }

    // Cholesky A = L L^H in place (A is HPD thanks to diagonal loading)
    float invd[kC];
#pragma unroll
    for (int j = 0; j < kC; ++j) {
      float d = Ar[j][j];
#pragma unroll
      for (int k2 = 0; k2 < j; ++k2)
        d -= Ar[j][k2] * Ar[j][k2] + Ai[j][k2] * Ai[j][k2];
      d = fmaxf(d, 1e-30f);
      float ljj = sqrtf(d);
      float inv = 1.f / ljj;
      Ar[j][j] = ljj;
      invd[j] = inv;
#pragma unroll
      for (int i = j + 1; i < kC; ++i) {
        float re = Ar[i][j], im = Ai[i][j];
#pragma unroll
        for (int k2 = 0; k2 < j; ++k2) {
          re -= Ar[i][k2] * Ar[j][k2] + Ai[i][k2] * Ai[j][k2];
          im -= Ai[i][k2] * Ar[j][k2] - Ar[i][k2] * Ai[j][k2];
        }
        Ar[i][j] = re * inv;
        Ai[i][j] = im * inv;
      }
    }

    // Solve A * N = S per column; need diag(N) (trace) and N[:,0] (weights)
    float trR = 0.f, trI = 0.f;
    float w0r[kC], w0i[kC];
#pragma unroll
    for (int m = 0; m < kC; ++m) {
      float yr[kC], yi[kC];
#pragma unroll
      for (int i = 0; i < kC; ++i) {
        float re = Sr[i][m], im = Si[i][m];
#pragma unroll
        for (int k2 = 0; k2 < i; ++k2) {
          re -= Ar[i][k2] * yr[k2] - Ai[i][k2] * yi[k2];
          im -= Ar[i][k2] * yi[k2] + Ai[i][k2] * yr[k2];
        }
        yr[i] = re * invd[i];
        yi[i] = im * invd[i];
      }
#pragma unroll
      for (int i = kC - 1; i >= 0; --i) {
        float re = yr[i], im = yi[i];
#pragma unroll
        for (int k2 = i + 1; k2 < kC; ++k2) {
          // conj(L[k][i]) * x[k]
          re -= Ar[k2][i] * yr[k2] + Ai[k2][i] * yi[k2];
          im -= Ar[k2][i] * yi[k2] - Ai[k2][i] * yr[k2];
        }
        yr[i] = re * invd[i];
        yi[i] = im * invd[i];
      }
      trR += yr[m];
      trI += yi[m];
      if (m == 0) {
#pragma unroll
        for (int c = 0; c < kC; ++c) { w0r[c] = yr[c]; w0i[c] = yi[c]; }
      }
    }

    float dr = trR + 1e-8f, di = trI;
    float idn = 1.f / (dr * dr + di * di);
#pragma unroll
    for (int c = 0; c < kC; ++c) {
      sW[2 * c]     = (w0r[c] * dr + w0i[c] * di) * idn;
      sW[2 * c + 1] = (w0i[c] * dr - w0r[c] * di) * idn;
    }
  }
  __syncthreads();

  // ---- beamform: out[t] = sum_c conj(w[c]) * X[c,t] ----
  // PLANAR complex output: real plane (B,F,T) then imag plane (B,F,T).
  float wr[kC], wi[kC];
#pragma unroll
  for (int c = 0; c < kC; ++c) {
    wr[c] = sW[2 * c];
    wi[c] = sW[2 * c + 1];
  }
  const size_t plane = (size_t)kB * kF * kT;
  for (int t = tid; t < kT; t += THREADS) {
    float o_r = 0.f, o_i = 0.f;
#pragma unroll
    for (int c = 0; c < kC; ++c) {
      float xr = sXr[c * kT + t];
      float xi = sXi[c * kT + t];
      o_r += wr[c] * xr + wi[c] * xi;
      o_i += wr[c] * xi - wi[c] * xr;
    }
    size_t idx = (size_t)bf * kT + t;
    if (idx < (size_t)out_elems)         out[idx]         = o_r;
    if (idx + plane < (size_t)out_elems) out[idx + plane] = o_i;
  }
}

extern "C" void kernel_launch(void* const* d_in, const int* in_sizes, int n_in,
                              void* d_out, int out_size, void* d_ws, size_t ws_size,
                              hipStream_t stream) {
  // Inputs identified by element count (specs: B*F*C*T, masks: B*F*T),
  // preserving dict order within each size class.
  const float* spec[2] = {nullptr, nullptr};
  const float* mask[2] = {nullptr, nullptr};
  int ns = 0, nm = 0;
  for (int i = 0; i < n_in; ++i) {
    if (in_sizes[i] == kB * kF * kC * kT) { if (ns < 2) spec[ns++] = (const float*)d_in[i]; }
    else if (in_sizes[i] == kB * kF * kT) { if (nm < 2) mask[nm++] = (const float*)d_in[i]; }
  }
  const float* spec_real = spec[0] ? spec[0] : (const float*)d_in[0];
  const float* spec_imag = spec[1] ? spec[1] : (const float*)d_in[1];
  const float* mask_s    = mask[0] ? mask[0] : (const float*)d_in[2];
  const float* mask_n    = mask[1] ? mask[1] : (const float*)d_in[3];

  int spec_elems = kB * kF * kC * kT;
  int mask_elems = kB * kF * kT;

  dim3 grid(kB * kF);
  dim3 block(THREADS);
  hipLaunchKernelGGL(mvdr_kernel, grid, block, 0, stream,
                     spec_real, spec_imag, mask_s, mask_n,
                     (float*)d_out, spec_elems, mask_elems, out_size);
}

// Round 2
// 295.678 us; speedup vs baseline: 1.5027x; 1.2332x over previous
//
#include <hip/hip_runtime.h>

constexpr int kB = 4;
constexpr int kF = 1025;
constexpr int kC = 6;
constexpr int kT = 1000;
constexpr int kBF = kB * kF;
// Per-group accumulator layout: [0..5] diag, [6..20] re, [21..35] im, [36] masksum
constexpr int NACCG = 37;
constexpr int THREADS = 256;
// Workspace layout (floats): per bf, PSD block of 80 (S at [0..36], N at [40..76]),
// then weights region: per bf 16 floats (12 used).
constexpr int PSD_STRIDE = 80;
constexpr int W_STRIDE = 16;

// ---------------- Kernel 1: PSD accumulation ----------------
__global__ __launch_bounds__(THREADS)
void psd_kernel(const float* __restrict__ spec_real,
                const float* __restrict__ spec_imag,
                const float* __restrict__ mask_s,
                const float* __restrict__ mask_n,
                float* __restrict__ ws_psd,
                int spec_elems, int mask_elems) {
  const int bf   = blockIdx.x;
  const int tid  = threadIdx.x;
  const int lane = tid & 63;
  const int wave = tid >> 6;
  const int grp  = tid >> 7;      // 0 -> mask_s stats, 1 -> mask_n stats
  const int gtid = tid & 127;

  __shared__ float sRed[4 * NACCG];

  const size_t sbase = (size_t)bf * (kC * kT);
  const size_t mbase = (size_t)bf * kT;
  const bool spec_ok = (sbase + (size_t)(kC * kT)) <= (size_t)spec_elems;
  const bool mask_ok = (mbase + (size_t)kT) <= (size_t)mask_elems;

  const float* __restrict__ mptr = (grp == 0) ? mask_s : mask_n;
  const float* __restrict__ xrb = spec_real + sbase;
  const float* __restrict__ xib = spec_imag + sbase;

  float acc[NACCG];
#pragma unroll
  for (int j = 0; j < NACCG; ++j) acc[j] = 0.f;

  for (int t = gtid; t < kT; t += 128) {
    float xr[kC], xi[kC];
#pragma unroll
    for (int c = 0; c < kC; ++c) {
      xr[c] = spec_ok ? xrb[c * kT + t] : 0.f;
      xi[c] = spec_ok ? xib[c * kT + t] : 0.f;
    }
    float m = mask_ok ? mptr[mbase + t] : 0.f;
    acc[36] += m;
#pragma unroll
    for (int c = 0; c < kC; ++c) {
      float p = xr[c] * xr[c] + xi[c] * xi[c];
      acc[c] += m * p;
    }
    int k = 0;
#pragma unroll
    for (int c = 0; c < kC; ++c) {
#pragma unroll
      for (int e = c + 1; e < kC; ++e) {
        float pr = xr[c] * xr[e] + xi[c] * xi[e];
        float pi = xi[c] * xr[e] - xr[c] * xi[e];
        acc[6  + k] += m * pr;
        acc[21 + k] += m * pi;
        ++k;
      }
    }
  }

  // wave shuffle reduction, then cross-wave combine via LDS
#pragma unroll
  for (int j = 0; j < NACCG; ++j) {
    float v = acc[j];
#pragma unroll
    for (int off = 32; off > 0; off >>= 1)
      v += __shfl_down(v, off, 64);
    if (lane == 0) sRed[wave * NACCG + j] = v;
  }
  __syncthreads();
  if (tid < NACCG) {
    float s = sRed[tid]             + sRed[NACCG + tid];      // waves 0,1 (mask_s)
    float n = sRed[2 * NACCG + tid] + sRed[3 * NACCG + tid];  // waves 2,3 (mask_n)
    float* wsbf = ws_psd + (size_t)bf * PSD_STRIDE;
    wsbf[tid]      = s;
    wsbf[40 + tid] = n;
  }
}

// ---------------- Kernel 2: per-bf MVDR solve (one thread per bf) ----------------
__global__ __launch_bounds__(64)
void solve_kernel(const float* __restrict__ ws_psd,
                  float* __restrict__ ws_w, int nbf) {
  const int bf = blockIdx.x * 64 + threadIdx.x;
  if (bf >= nbf) return;
  const float* f = ws_psd + (size_t)bf * PSD_STRIDE;
  // S: diag f[0..5], re f[6..20], im f[21..35], sum f[36]
  // N: diag f[40..45], re f[46..60], im f[61..75], sum f[76]
  float isS = 1.f / (f[36] + 1e-15f);
  float isN = 1.f / (f[76] + 1e-15f);

  float trN = 0.f;
#pragma unroll
  for (int c = 0; c < kC; ++c) trN += f[40 + c];
  trN *= isN;
  float epsl = trN * 1e-7f + 1e-8f;

  float Sr[kC][kC], Si[kC][kC];
  float Ar[kC][kC], Ai[kC][kC];
#pragma unroll
  for (int c = 0; c < kC; ++c) {
    Sr[c][c] = f[c] * isS;              Si[c][c] = 0.f;
    Ar[c][c] = f[40 + c] * isN + epsl;  Ai[c][c] = 0.f;
  }
  {
    int k = 0;
#pragma unroll
    for (int c = 0; c < kC; ++c) {
#pragma unroll
      for (int e = c + 1; e < kC; ++e) {
        float spr = f[6  + k] * isS, spi = f[21 + k] * isS;
        Sr[c][e] = spr;  Si[c][e] = spi;
        Sr[e][c] = spr;  Si[e][c] = -spi;
        float npr = f[46 + k] * isN, npi = f[61 + k] * isN;
        Ar[c][e] = npr;  Ai[c][e] = npi;
        Ar[e][c] = npr;  Ai[e][c] = -npi;
        ++k;
      }
    }
  }

  // Cholesky A = L L^H in place
  float invd[kC];
#pragma unroll
  for (int j = 0; j < kC; ++j) {
    float d = Ar[j][j];
#pragma unroll
    for (int k2 = 0; k2 < j; ++k2)
      d -= Ar[j][k2] * Ar[j][k2] + Ai[j][k2] * Ai[j][k2];
    d = fmaxf(d, 1e-30f);
    float ljj = sqrtf(d);
    float inv = 1.f / ljj;
    Ar[j][j] = ljj;
    invd[j] = inv;
#pragma unroll
    for (int i = j + 1; i < kC; ++i) {
      float re = Ar[i][j], im = Ai[i][j];
#pragma unroll
      for (int k2 = 0; k2 < j; ++k2) {
        re -= Ar[i][k2] * Ar[j][k2] + Ai[i][k2] * Ai[j][k2];
        im -= Ai[i][k2] * Ar[j][k2] - Ar[i][k2] * Ai[j][k2];
      }
      Ar[i][j] = re * inv;
      Ai[i][j] = im * inv;
    }
  }

  // Solve A * N = S per column; need diag(N) (trace) and N[:,0]
  float trR = 0.f, trI = 0.f;
  float w0r[kC], w0i[kC];
#pragma unroll
  for (int m = 0; m < kC; ++m) {
    float yr[kC], yi[kC];
#pragma unroll
    for (int i = 0; i < kC; ++i) {
      float re = Sr[i][m], im = Si[i][m];
#pragma unroll
      for (int k2 = 0; k2 < i; ++k2) {
        re -= Ar[i][k2] * yr[k2] - Ai[i][k2] * yi[k2];
        im -= Ar[i][k2] * yi[k2] + Ai[i][k2] * yr[k2];
      }
      yr[i] = re * invd[i];
      yi[i] = im * invd[i];
    }
#pragma unroll
    for (int i = kC - 1; i >= 0; --i) {
      float re = yr[i], im = yi[i];
#pragma unroll
      for (int k2 = i + 1; k2 < kC; ++k2) {
        re -= Ar[k2][i] * yr[k2] + Ai[k2][i] * yi[k2];
        im -= Ar[k2][i] * yi[k2] - Ai[k2][i] * yr[k2];
      }
      yr[i] = re * invd[i];
      yi[i] = im * invd[i];
    }
    trR += yr[m];
    trI += yi[m];
    if (m == 0) {
#pragma unroll
      for (int c = 0; c < kC; ++c) { w0r[c] = yr[c]; w0i[c] = yi[c]; }
    }
  }

  float dr = trR + 1e-8f, di = trI;
  float idn = 1.f / (dr * dr + di * di);
  float* w = ws_w + (size_t)bf * W_STRIDE;
#pragma unroll
  for (int c = 0; c < kC; ++c) {
    w[2 * c]     = (w0r[c] * dr + w0i[c] * di) * idn;
    w[2 * c + 1] = (w0i[c] * dr - w0r[c] * di) * idn;
  }
}

// ---------------- Kernel 3: beamform ----------------
__global__ __launch_bounds__(THREADS)
void bf_kernel(const float* __restrict__ spec_real,
               const float* __restrict__ spec_imag,
               const float* __restrict__ ws_w,
               float* __restrict__ out,
               int spec_elems, int out_elems) {
  const int bf  = blockIdx.x;
  const int tid = threadIdx.x;

  __shared__ float sW[2 * kC];
  if (tid < 2 * kC) sW[tid] = ws_w[(size_t)bf * W_STRIDE + tid];
  __syncthreads();

  float wr[kC], wi[kC];
#pragma unroll
  for (int c = 0; c < kC; ++c) {
    wr[c] = sW[2 * c];
    wi[c] = sW[2 * c + 1];
  }

  const size_t sbase = (size_t)bf * (kC * kT);
  const bool spec_ok = (sbase + (size_t)(kC * kT)) <= (size_t)spec_elems;
  const float* __restrict__ xrb = spec_real + sbase;
  const float* __restrict__ xib = spec_imag + sbase;
  const size_t plane = (size_t)kB * kF * kT;

  for (int t = tid; t < kT; t += THREADS) {
    float o_r = 0.f, o_i = 0.f;
#pragma unroll
    for (int c = 0; c < kC; ++c) {
      float xr = spec_ok ? xrb[c * kT + t] : 0.f;
      float xi = spec_ok ? xib[c * kT + t] : 0.f;
      o_r += wr[c] * xr + wi[c] * xi;
      o_i += wr[c] * xi - wi[c] * xr;
    }
    size_t idx = (size_t)bf * kT + t;
    if (idx < (size_t)out_elems)         out[idx]         = o_r;
    if (idx + plane < (size_t)out_elems) out[idx + plane] = o_i;
  }
}

// ---------------- Fallback: monolithic kernel (round-1, used if ws too small) ----------------
__global__ __launch_bounds__(THREADS)
void mvdr_kernel(const float* __restrict__ spec_real,
                 const float* __restrict__ spec_imag,
                 const float* __restrict__ mask_s,
                 const float* __restrict__ mask_n,
                 float* __restrict__ out,
                 int spec_elems, int mask_elems, int out_elems) {
  const int bf   = blockIdx.x;
  const int tid  = threadIdx.x;
  const int lane = tid & 63;
  const int wave = tid >> 6;
  const int grp  = tid >> 7;
  const int gtid = tid & 127;

  __shared__ __align__(16) float sXr[kC * kT];
  __shared__ __align__(16) float sXi[kC * kT];
  __shared__ float sRed[4 * NACCG];
  __shared__ float sFin[74];
  __shared__ float sW[2 * kC];

  const size_t sbase = (size_t)bf * (kC * kT);
  const size_t mbase = (size_t)bf * kT;
  const bool spec_ok = (sbase + (size_t)(kC * kT)) <= (size_t)spec_elems;
  const bool mask_ok = (mbase + (size_t)kT) <= (size_t)mask_elems;

  if (spec_ok) {
    const float4* gr4 = reinterpret_cast<const float4*>(spec_real + sbase);
    const float4* gi4 = reinterpret_cast<const float4*>(spec_imag + sbase);
    float4* lr4 = reinterpret_cast<float4*>(sXr);
    float4* li4 = reinterpret_cast<float4*>(sXi);
    for (int i = tid; i < (kC * kT) / 4; i += THREADS) {
      lr4[i] = gr4[i];
      li4[i] = gi4[i];
    }
  } else {
    for (int i = tid; i < kC * kT; i += THREADS) { sXr[i] = 0.f; sXi[i] = 0.f; }
  }
  __syncthreads();

  const float* __restrict__ mptr = (grp == 0) ? mask_s : mask_n;
  float acc[NACCG];
#pragma unroll
  for (int j = 0; j < NACCG; ++j) acc[j] = 0.f;

  for (int t = gtid; t < kT; t += 128) {
    float xr[kC], xi[kC];
#pragma unroll
    for (int c = 0; c < kC; ++c) {
      xr[c] = sXr[c * kT + t];
      xi[c] = sXi[c * kT + t];
    }
    float m = mask_ok ? mptr[mbase + t] : 0.f;
    acc[36] += m;
#pragma unroll
    for (int c = 0; c < kC; ++c) {
      float p = xr[c] * xr[c] + xi[c] * xi[c];
      acc[c] += m * p;
    }
    int k = 0;
#pragma unroll
    for (int c = 0; c < kC; ++c) {
#pragma unroll
      for (int e = c + 1; e < kC; ++e) {
        float pr = xr[c] * xr[e] + xi[c] * xi[e];
        float pi = xi[c] * xr[e] - xr[c] * xi[e];
        acc[6  + k] += m * pr;
        acc[21 + k] += m * pi;
        ++k;
      }
    }
  }

#pragma unroll
  for (int j = 0; j < NACCG; ++j) {
    float v = acc[j];
#pragma unroll
    for (int off = 32; off > 0; off >>= 1)
      v += __shfl_down(v, off, 64);
    if (lane == 0) sRed[wave * NACCG + j] = v;
  }
  __syncthreads();
  if (tid < NACCG) {
    float s = sRed[tid]             + sRed[NACCG + tid];
    float n = sRed[2 * NACCG + tid] + sRed[3 * NACCG + tid];
    if (tid < 36) {
      sFin[tid]      = s;
      sFin[36 + tid] = n;
    } else {
      sFin[72] = s;
      sFin[73] = n;
    }
  }
  __syncthreads();

  if (tid == 0) {
    float isS = 1.f / (sFin[72] + 1e-15f);
    float isN = 1.f / (sFin[73] + 1e-15f);
    float trN = 0.f;
#pragma unroll
    for (int c = 0; c < kC; ++c) trN += sFin[36 + c];
    trN *= isN;
    float epsl = trN * 1e-7f + 1e-8f;

    float Sr[kC][kC], Si[kC][kC];
    float Ar[kC][kC], Ai[kC][kC];
#pragma unroll
    for (int c = 0; c < kC; ++c) {
      Sr[c][c] = sFin[c] * isS;             Si[c][c] = 0.f;
      Ar[c][c] = sFin[36 + c] * isN + epsl; Ai[c][c] = 0.f;
    }
    {
      int k = 0;
#pragma unroll
      for (int c = 0; c < kC; ++c) {
#pragma unroll
        for (int e = c + 1; e < kC; ++e) {
          float spr = sFin[6  + k] * isS, spi = sFin[21 + k] * isS;
          Sr[c][e] = spr;  Si[c][e] = spi;
          Sr[e][c] = spr;  Si[e][c] = -spi;
          float npr = sFin[42 + k] * isN, npi = sFin[57 + k] * isN;
          Ar[c][e] = npr;  Ai[c][e] = npi;
          Ar[e][c] = npr;  Ai[e][c] = -npi;
          ++k;
        }
      }
    }

    float invd[kC];
#pragma unroll
    for (int j = 0; j < kC; ++j) {
      float d = Ar[j][j];
#pragma unroll
      for (int k2 = 0; k2 < j; ++k2)
        d -= Ar[j][k2] * Ar[j][k2] + Ai[j][k2] * Ai[j][k2];
      d = fmaxf(d, 1e-30f);
      float ljj = sqrtf(d);
      float inv = 1.f / ljj;
      Ar[j][j] = ljj;
      invd[j] = inv;
#pragma unroll
      for (int i = j + 1; i < kC; ++i) {
        float re = Ar[i][j], im = Ai[i][j];
#pragma unroll
        for (int k2 = 0; k2 < j; ++k2) {
          re -= Ar[i][k2] * Ar[j][k2] + Ai[i][k2] * Ai[j][k2];
          im -= Ai[i][k2] * Ar[j][k2] - Ar[i][k2] * Ai[j][k2];
        }
        Ar[i][j] = re * inv;
        Ai[i][j] = im * inv;
      }
    }

    float trR = 0.f, trI = 0.f;
    float w0r[kC], w0i[kC];
#pragma unroll
    for (int m = 0; m < kC; ++m) {
      float yr[kC], yi[kC];
#pragma unroll
      for (int i = 0; i < kC; ++i) {
        float re = Sr[i][m], im = Si[i][m];
#pragma unroll
        for (int k2 = 0; k2 < i; ++k2) {
          re -= Ar[i][k2] * yr[k2] - Ai[i][k2] * yi[k2];
          im -= Ar[i][k2] * yi[k2] + Ai[i][k2] * yr[k2];
        }
        yr[i] = re * invd[i];
        yi[i] = im * invd[i];
      }
#pragma unroll
      for (int i = kC - 1; i >= 0; --i) {
        float re = yr[i], im = yi[i];
#pragma unroll
        for (int k2 = i + 1; k2 < kC; ++k2) {
          re -= Ar[k2][i] * yr[k2] + Ai[k2][i] * yi[k2];
          im -= Ar[k2][i] * yi[k2] - Ai[k2][i] * yr[k2];
        }
        yr[i] = re * invd[i];
        yi[i] = im * invd[i];
      }
      trR += yr[m];
      trI += yi[m];
      if (m == 0) {
#pragma unroll
        for (int c = 0; c < kC; ++c) { w0r[c] = yr[c]; w0i[c] = yi[c]; }
      }
    }

    float dr = trR + 1e-8f, di = trI;
    float idn = 1.f / (dr * dr + di * di);
#pragma unroll
    for (int c = 0; c < kC; ++c) {
      sW[2 * c]     = (w0r[c] * dr + w0i[c] * di) * idn;
      sW[2 * c + 1] = (w0i[c] * dr - w0r[c] * di) * idn;
    }
  }
  __syncthreads();

  float wr[kC], wi[kC];
#pragma unroll
  for (int c = 0; c < kC; ++c) {
    wr[c] = sW[2 * c];
    wi[c] = sW[2 * c + 1];
  }
  const size_t plane = (size_t)kB * kF * kT;
  for (int t = tid; t < kT; t += THREADS) {
    float o_r = 0.f, o_i = 0.f;
#pragma unroll
    for (int c = 0; c < kC; ++c) {
      float xr = sXr[c * kT + t];
      float xi = sXi[c * kT + t];
      o_r += wr[c] * xr + wi[c] * xi;
      o_i += wr[c] * xi - wi[c] * xr;
    }
    size_t idx = (size_t)bf * kT + t;
    if (idx < (size_t)out_elems)         out[idx]         = o_r;
    if (idx + plane < (size_t)out_elems) out[idx + plane] = o_i;
  }
}

extern "C" void kernel_launch(void* const* d_in, const int* in_sizes, int n_in,
                              void* d_out, int out_size, void* d_ws, size_t ws_size,
                              hipStream_t stream) {
  const float* spec[2] = {nullptr, nullptr};
  const float* mask[2] = {nullptr, nullptr};
  int ns = 0, nm = 0;
  for (int i = 0; i < n_in; ++i) {
    if (in_sizes[i] == kB * kF * kC * kT) { if (ns < 2) spec[ns++] = (const float*)d_in[i]; }
    else if (in_sizes[i] == kB * kF * kT) { if (nm < 2) mask[nm++] = (const float*)d_in[i]; }
  }
  const float* spec_real = spec[0] ? spec[0] : (const float*)d_in[0];
  const float* spec_imag = spec[1] ? spec[1] : (const float*)d_in[1];
  const float* mask_s    = mask[0] ? mask[0] : (const float*)d_in[2];
  const float* mask_n    = mask[1] ? mask[1] : (const float*)d_in[3];

  int spec_elems = kB * kF * kC * kT;
  int mask_elems = kB * kF * kT;

  const size_t need = (size_t)kBF * (PSD_STRIDE + W_STRIDE) * sizeof(float);
  if (d_ws != nullptr && ws_size >= need) {
    float* ws_psd = (float*)d_ws;
    float* ws_w   = ws_psd + (size_t)kBF * PSD_STRIDE;
    hipLaunchKernelGGL(psd_kernel, dim3(kBF), dim3(THREADS), 0, stream,
                       spec_real, spec_imag, mask_s, mask_n,
                       ws_psd, spec_elems, mask_elems);
    hipLaunchKernelGGL(solve_kernel, dim3((kBF + 63) / 64), dim3(64), 0, stream,
                       ws_psd, ws_w, kBF);
    hipLaunchKernelGGL(bf_kernel, dim3(kBF), dim3(THREADS), 0, stream,
                       spec_real, spec_imag, ws_w,
                       (float*)d_out, spec_elems, out_size);
  } else {
    dim3 grid(kBF);
    dim3 block(THREADS);
    hipLaunchKernelGGL(mvdr_kernel, grid, block, 0, stream,
                       spec_real, spec_imag, mask_s, mask_n,
                       (float*)d_out, spec_elems, mask_elems, out_size);
  }
}